// Round 9
// baseline (107.735 us; speedup 1.0000x reference)
//
#include <hip/hip_runtime.h>
#include <math.h>

typedef float f32x4 __attribute__((ext_vector_type(4)));
typedef short s16x8 __attribute__((ext_vector_type(8)));
typedef unsigned u32x4 __attribute__((ext_vector_type(4)));

#define N_NODES 2048
#define KEDGE 32
#define HDIM 128
#define HE_LIM (134217728u - 16u)   // total hE bytes - 16

__device__ __forceinline__ short f2bf(float f){
  unsigned u = __builtin_bit_cast(unsigned, f);
  u += 0x7fffu + ((u >> 16) & 1u);
  return (short)(u >> 16);
}

__device__ __forceinline__ unsigned cvt_pk_bf16(float a, float b){
  unsigned r;
  asm("v_cvt_pk_bf16_f32 %0, %1, %2" : "=v"(r) : "v"(a), "v"(b));
  return r;
}

// tanh-form GELU via exp2+rcp: max abs error vs exact ~5e-4
__device__ __forceinline__ float fast_gelu(float x){
  float t = x * (-2.3022078f - 0.1029527f * x * x);
  float e = __builtin_amdgcn_exp2f(t);
  return x * __builtin_amdgcn_rcpf(1.0f + e);
}

__device__ __forceinline__ void gld16(const void* g, void* l){
  __builtin_amdgcn_global_load_lds(
      (const __attribute__((address_space(1))) void*)g,
      (__attribute__((address_space(3))) void*)l, 16, 0, 0);
}

__device__ __forceinline__ f32x4 mfma16(s16x8 a, s16x8 b, f32x4 c){
  return __builtin_amdgcn_mfma_f32_16x16x32_bf16(a, b, c, 0, 0, 0);
}

// ---- prep kernel 1: pack W1/W2 to bf16 B-fragment order; init idx flag ----
// elem((ks,ct,lane,j)) = W[ks*32 + (lane>>4)*8 + j][ct*16 + (lane&15)]
__global__ void prep1(const float* __restrict__ W1, const float* __restrict__ W2,
                      short* __restrict__ W1f, short* __restrict__ W2f,
                      unsigned* __restrict__ flag){
  if (blockIdx.x == 320){
    if (threadIdx.x == 0) *flag = 0u;
    return;
  }
  int t = blockIdx.x * 256 + threadIdx.x;
  if (t < 65536){
    int ks = t >> 12, r = t & 4095;
    int ct = r >> 9;  r &= 511;
    int lane = r >> 3, j = r & 7;
    int k = ks*32 + (lane>>4)*8 + j;
    int n = ct*16 + (lane&15);
    W1f[t] = f2bf(W1[k*128 + n]);
  } else if (t < 81920){
    int t2 = t - 65536;
    int ks = t2 >> 12, r = t2 & 4095;
    int ct = r >> 9;  r &= 511;
    int lane = r >> 3, j = r & 7;
    int k = ks*32 + (lane>>4)*8 + j;
    int n = ct*16 + (lane&15);
    W2f[t2] = f2bf(W2[k*128 + n]);
  }
}

// ---- prep kernel 2: Zb (bf16, row layout) + U tables, + E_idx dtype detect
//   Zb[m] = bf16( hS(m)@W1c + hV(m)@W1d )      (128 bf16 per node)
//   U[m]  = hV(m)@W1a + b1                     (f32, 128)
__global__ __launch_bounds__(256)
void prep2(const float* __restrict__ hS, const float* __restrict__ hV,
           const float* __restrict__ b1, const short* __restrict__ W1f,
           short* __restrict__ Zb, float* __restrict__ U,
           const unsigned* __restrict__ Ei_u, unsigned* __restrict__ flag){
  if (blockIdx.x >= 128){
    int t = ((int)blockIdx.x - 128)*256 + threadIdx.x;   // t < 131072
    unsigned v = Ei_u[2*t + 1];
    unsigned long long m = __ballot(v != 0u);
    if ((threadIdx.x & 63) == 0 && m) atomicOr(flag, 1u);
    return;
  }
  const int tid = threadIdx.x;
  const int w = tid >> 6, lane = tid & 63, l15 = lane & 15, lg = lane >> 4;
  const int nb = ((int)blockIdx.x*4 + w)*16;

  f32x4 accz[8], accu[8];
  #pragma unroll
  for (int ct = 0; ct < 8; ++ct){ accz[ct] = (f32x4){0,0,0,0}; accu[ct] = (f32x4){0,0,0,0}; }

  #pragma unroll
  for (int ks = 0; ks < 4; ++ks){
    const float* p = hS + (long)(nb + l15)*128 + ks*32 + lg*8;
    float4 x = *(const float4*)p, y = *(const float4*)(p + 4);
    u32x4 pk;
    pk[0] = cvt_pk_bf16(x.x, x.y); pk[1] = cvt_pk_bf16(x.z, x.w);
    pk[2] = cvt_pk_bf16(y.x, y.y); pk[3] = cvt_pk_bf16(y.z, y.w);
    s16x8 a = __builtin_bit_cast(s16x8, pk);
    #pragma unroll
    for (int ct = 0; ct < 8; ++ct){
      s16x8 bf = *(const s16x8*)(W1f + (8+ks)*4096 + ct*512 + lane*8);
      accz[ct] = mfma16(a, bf, accz[ct]);
    }
  }
  #pragma unroll
  for (int ks = 0; ks < 4; ++ks){
    const float* p = hV + (long)(nb + l15)*128 + ks*32 + lg*8;
    float4 x = *(const float4*)p, y = *(const float4*)(p + 4);
    u32x4 pk;
    pk[0] = cvt_pk_bf16(x.x, x.y); pk[1] = cvt_pk_bf16(x.z, x.w);
    pk[2] = cvt_pk_bf16(y.x, y.y); pk[3] = cvt_pk_bf16(y.z, y.w);
    s16x8 a = __builtin_bit_cast(s16x8, pk);
    #pragma unroll
    for (int ct = 0; ct < 8; ++ct){
      s16x8 bfd = *(const s16x8*)(W1f + (12+ks)*4096 + ct*512 + lane*8);
      accz[ct] = mfma16(a, bfd, accz[ct]);
      s16x8 bfa = *(const s16x8*)(W1f + (0+ks)*4096 + ct*512 + lane*8);
      accu[ct] = mfma16(a, bfa, accu[ct]);
    }
  }

  float b1v[8];
  #pragma unroll
  for (int ct = 0; ct < 8; ++ct) b1v[ct] = b1[ct*16 + l15];

  #pragma unroll
  for (int ct = 0; ct < 8; ++ct)
    #pragma unroll
    for (int i = 0; i < 4; ++i){
      const long row = nb + lg*4 + i;
      Zb[row*128 + ct*16 + l15] = f2bf(accz[ct][i]);
      U[row*128 + ct*16 + l15]  = accu[ct][i] + b1v[ct];
    }
}

// ---- fused kernel: persistent pipelined. grid=256 (1 block/CU), 4 waves.
// wave = half-node (16 edges) per iteration, T=16 iterations.
// Pipeline: stage(t+1) 9 gld16 -> vmcnt(9) (stage(t) issued a full iter ago)
// -> next-state register loads -> compute(t) (LDS+regs ONLY).
__global__ __launch_bounds__(256, 1)
void fusedF(const float* __restrict__ hE, const int* __restrict__ Eidx,
            const float* __restrict__ mask, const float* __restrict__ hV,
            const float* __restrict__ W2b, const float* __restrict__ lng,
            const float* __restrict__ lnb, const short* __restrict__ W1f,
            const short* __restrict__ W2f, const short* __restrict__ Zb,
            const float* __restrict__ U, const unsigned* __restrict__ idx_flag,
            float* __restrict__ out)
{
  // [0,73728): hE dbuf, wave w at w*18432, 2 x 9216 (16 rows x 528B padded)
  // [73728,106496): W1b staged; [106496,139264): W2 staged; [139264,141312): vex
  __shared__ __align__(16) char smem[141312];

  const int tid  = threadIdx.x;
  const int w    = tid >> 6;
  const int lane = tid & 63;
  const int l15  = lane & 15;
  const int lg   = lane >> 4;
  const int h    = w & 1;            // half of the node
  const int p    = w >> 1;           // node-pair within block

  const int node0 = (int)blockIdx.x * 32 + p*16;
  const long zrow0 = (long)(node0 >> 11) * N_NODES;   // BATCH BASE ROW (r8 bug fix)

  char*  mybuf = smem + w*18432;
  char*  W1L   = smem + 73728;
  char*  W2L   = smem + 106496;
  float* VEX   = (float*)(smem + 139264);

  // padded-stage source offsets: chunk q, slot t=q*64+lane -> row t/33, gran t%33
  unsigned pre[9];
  #pragma unroll
  for (int q = 0; q < 9; ++q){
    unsigned t = (unsigned)(q*64 + lane);
    unsigned r = (t * 1986u) >> 16;          // t/33 for t < 1089
    unsigned g = t - r*33u;
    pre[q] = r*512u + g*16u;                 // g==32 pad -> next row start (valid)
  }

  // stage W1b (32KB) + W2 (32KB) once, cooperatively
  #pragma unroll
  for (int q = 0; q < 8; ++q)
    gld16((const char*)W1f + 32768 + (w*8+q)*1024 + lane*16, W1L + (w*8+q)*1024);
  #pragma unroll
  for (int q = 0; q < 8; ++q)
    gld16((const char*)W2f + (w*8+q)*1024 + lane*16, W2L + (w*8+q)*1024);

  // stage hE(it=0)
  {
    const unsigned eb0 = (unsigned)(node0*16384 + h*8192);
    #pragma unroll
    for (int q = 0; q < 9; ++q){
      unsigned off = eb0 + pre[q]; off = off < HE_LIM ? off : HE_LIM;
      gld16((const char*)hE + off, mybuf + q*1024);
    }
  }

  const int is64 = (*idx_flag == 0u);

  // per-iter-constant epilogue params (prefetched: compute must be VMEM-free)
  float w2b8[8], lngv, lnbv;
  #pragma unroll
  for (int ct = 0; ct < 8; ++ct) w2b8[ct] = W2b[ct*16 + l15];
  { const int c = (lg*2 + h)*16 + l15; lngv = lng[c]; lnbv = lnb[c]; }

  // identity B-fragments for Z injection (exact in bf16)
  s16x8 ifr[2];
  #pragma unroll
  for (int c2 = 0; c2 < 2; ++c2){
    const int active = ((lg >> 1) == c2);
    const int j = l15 - 8*(lg & 1);
    s16x8 f;
    #pragma unroll
    for (int e = 0; e < 8; ++e)
      f[e] = (active && j == e) ? (short)0x3F80 : (short)0;
    ifr[c2] = f;
  }

  // scalar pipeline state: C = iter t, N = iter t+1
  float mvalC, mvalN; int eidxN;
  s16x8 zbC[4];
  float uvC[8], hvvC[8];
  {
    const int e0 = node0*32 + h*16 + l15;
    const int eidx0 = is64 ? Eidx[2*e0] : Eidx[e0];
    mvalC = mask[e0];
    #pragma unroll
    for (int ks = 0; ks < 4; ++ks)
      zbC[ks] = *(const s16x8*)(Zb + (zrow0 + eidx0)*128 + ks*32 + lg*8);
    #pragma unroll
    for (int ct = 0; ct < 8; ++ct){
      uvC[ct]  = U[(long)node0*128 + ct*16 + l15];
      hvvC[ct] = hV[(long)node0*128 + ct*16 + l15];
    }
    const int e1 = (node0+1)*32 + h*16 + l15;
    eidxN = is64 ? Eidx[2*e1] : Eidx[e1];
    mvalN = mask[e1];
  }

  asm volatile("s_waitcnt vmcnt(0)" ::: "memory");   // cold-start drain (once)
  __builtin_amdgcn_sched_barrier(0);
  __builtin_amdgcn_s_barrier();                      // W1L/W2L visible to all

  for (int it = 0; it < 16; ++it){
    // ---- stage hE(it+1): EXACTLY 9 gld16 between fences ----
    const int jn = (it+1 < 16) ? it+1 : 15;
    const unsigned ebN = (unsigned)((node0+jn)*16384 + h*8192);
    __builtin_amdgcn_sched_barrier(0);
    #pragma unroll
    for (int q = 0; q < 9; ++q){
      unsigned off = ebN + pre[q]; off = off < HE_LIM ? off : HE_LIM;
      gld16((const char*)hE + off, mybuf + ((it+1)&1)*9216 + q*1024);
    }
    __builtin_amdgcn_sched_barrier(0);
    asm volatile("s_waitcnt vmcnt(9)" ::: "memory"); // stage(t)+older all done
    __builtin_amdgcn_sched_barrier(0);

    // ---- next-state register loads (counted waits, never drain stage) ----
    const int j2 = (it+2 < 16) ? it+2 : 15;
    const int e2 = (node0+j2)*32 + h*16 + l15;
    const int eidxP = is64 ? Eidx[2*e2] : Eidx[e2];
    const float mvalP = mask[e2];
    s16x8 zbN[4];
    #pragma unroll
    for (int ks = 0; ks < 4; ++ks)
      zbN[ks] = *(const s16x8*)(Zb + (zrow0 + eidxN)*128 + ks*32 + lg*8);
    float uvN[8], hvvN[8];
    #pragma unroll
    for (int ct = 0; ct < 8; ++ct){
      uvN[ct]  = U[(long)(node0+jn)*128 + ct*16 + l15];
      hvvN[ct] = hV[(long)(node0+jn)*128 + ct*16 + l15];
    }

    // ---- GEMM1 half-node: mask*(hE@W1b + Z[idx]) via LDS + reg A-frags ----
    f32x4 acc1[8];
    #pragma unroll
    for (int ct = 0; ct < 8; ++ct) acc1[ct] = (f32x4){0,0,0,0};

    const char* hbuf = mybuf + (it&1)*9216;
    #pragma unroll
    for (int ks = 0; ks < 4; ++ks){
      const char* pe = hbuf + l15*528 + ks*128 + lg*32;
      float4 ex = *(const float4*)pe;
      float4 ey = *(const float4*)(pe + 16);
      u32x4 pk;
      pk[0] = cvt_pk_bf16(ex.x, ex.y); pk[1] = cvt_pk_bf16(ex.z, ex.w);
      pk[2] = cvt_pk_bf16(ey.x, ey.y); pk[3] = cvt_pk_bf16(ey.z, ey.w);
      s16x8 a = __builtin_bit_cast(s16x8, pk);
      const char* bb = W1L + ks*8192 + lane*16;
      #pragma unroll
      for (int ct = 0; ct < 8; ++ct){
        s16x8 bf = *(const s16x8*)(bb + ct*1024);
        acc1[ct] = mfma16(a, bf, acc1[ct]);
      }
      #pragma unroll
      for (int c2 = 0; c2 < 2; ++c2)
        acc1[ks*2 + c2] = mfma16(zbC[ks], ifr[c2], acc1[ks*2 + c2]);
    }

    // ---- mask (per-row) + U + GELU, reduce 16 edges in-register ----
    float m_i[4];
    #pragma unroll
    for (int i = 0; i < 4; ++i) m_i[i] = __shfl(mvalC, lg*4 + i, 64);
    float v8[8];
    #pragma unroll
    for (int ct = 0; ct < 8; ++ct){
      float s = 0.f;
      #pragma unroll
      for (int i = 0; i < 4; ++i)
        s += fast_gelu(uvC[ct] + m_i[i]*acc1[ct][i]);
      s += __shfl_xor(s, 16, 64);
      s += __shfl_xor(s, 32, 64);
      v8[ct] = s;
    }

    // ---- exchange partial v with partner wave (raw barrier, no drain) ----
    float* vo = VEX + w*128;
    if (lg == 0){
      #pragma unroll
      for (int ct = 0; ct < 8; ++ct) vo[ct*16 + l15] = v8[ct];
    }
    asm volatile("s_waitcnt lgkmcnt(0)" ::: "memory");
    __builtin_amdgcn_sched_barrier(0);
    __builtin_amdgcn_s_barrier();

    // ---- GEMM2: (v_own + v_partner) @ W2 from LDS ----
    const float* vp = VEX + (w^1)*128;
    f32x4 acc2[8];
    #pragma unroll
    for (int ct = 0; ct < 8; ++ct) acc2[ct] = (f32x4){0,0,0,0};
    #pragma unroll
    for (int ks2 = 0; ks2 < 4; ++ks2){
      const int off = ks2*32 + lg*8;
      float4 a0 = *(const float4*)(vo + off);
      float4 a1 = *(const float4*)(vo + off + 4);
      float4 b0 = *(const float4*)(vp + off);
      float4 b1 = *(const float4*)(vp + off + 4);
      u32x4 pk;
      pk[0] = cvt_pk_bf16(a0.x+b0.x, a0.y+b0.y);
      pk[1] = cvt_pk_bf16(a0.z+b0.z, a0.w+b0.w);
      pk[2] = cvt_pk_bf16(a1.x+b1.x, a1.y+b1.y);
      pk[3] = cvt_pk_bf16(a1.z+b1.z, a1.w+b1.w);
      s16x8 av = __builtin_bit_cast(s16x8, pk);
      const char* wb2 = W2L + ks2*8192 + lane*16;
      #pragma unroll
      for (int ct = 0; ct < 8; ++ct){
        s16x8 bf = *(const s16x8*)(wb2 + ct*1024);
        acc2[ct] = mfma16(av, bf, acc2[ct]);
      }
    }
    __builtin_amdgcn_s_barrier();     // vex safe to overwrite next iter

    // ---- epilogue: +32*b2, /30, +h_V, LayerNorm; each wave stores 1 col/lane
    float res[8];
    float vs = 0.f, vq = 0.f;
    #pragma unroll
    for (int ct = 0; ct < 8; ++ct){
      float dh  = (acc2[ct][0] + 32.0f * w2b8[ct]) * (1.0f/30.0f);
      float val = hvvC[ct] + dh;
      res[ct] = val;
      vs += val; vq += val*val;
    }
    vs += __shfl_xor(vs, 1, 64);  vs += __shfl_xor(vs, 2, 64);
    vs += __shfl_xor(vs, 4, 64);  vs += __shfl_xor(vs, 8, 64);
    vq += __shfl_xor(vq, 1, 64);  vq += __shfl_xor(vq, 2, 64);
    vq += __shfl_xor(vq, 4, 64);  vq += __shfl_xor(vq, 8, 64);
    const float mu  = vs * (1.0f/128.0f);
    const float var = vq * (1.0f/128.0f) - mu*mu;
    const float rs  = rsqrtf(var + 1e-5f);

    {
      const int ct = lg*2 + h;          // wave h stores its column parity
      const int c  = ct*16 + l15;
      out[(long)(node0+it)*128 + c] = (res[ct] - mu) * rs * lngv + lnbv;
    }

    // ---- rotate pipeline state ----
    mvalC = mvalN; mvalN = mvalP; eidxN = eidxP;
    #pragma unroll
    for (int ks = 0; ks < 4; ++ks) zbC[ks] = zbN[ks];
    #pragma unroll
    for (int ct = 0; ct < 8; ++ct){ uvC[ct] = uvN[ct]; hvvC[ct] = hvvN[ct]; }
  }
}

extern "C" void kernel_launch(void* const* d_in, const int* in_sizes, int n_in,
                              void* d_out, int out_size, void* d_ws, size_t ws_size,
                              hipStream_t stream) {
  const float* hS  = (const float*)d_in[0];
  const float* hV  = (const float*)d_in[1];
  const float* hE  = (const float*)d_in[2];
  const int*   Ei  = (const int*)d_in[3];
  const float* mk  = (const float*)d_in[4];
  const float* W1w = (const float*)d_in[5];
  const float* W1b = (const float*)d_in[6];
  const float* W2w = (const float*)d_in[7];
  const float* W2b = (const float*)d_in[8];
  const float* lng = (const float*)d_in[9];
  const float* lnb = (const float*)d_in[10];

  short* W1f = (short*)d_ws;                           // 131072 B
  short* W2f = W1f + 65536;                            // 32768 B
  unsigned* flag = (unsigned*)((char*)d_ws + 163840);
  short* Zb = (short*)((char*)d_ws + 164096);          // 2 MB (bf16)
  float* U  = (float*)((char*)d_ws + 2261248);         // 4 MB

  prep1<<<321, 256, 0, stream>>>(W1w, W2w, W1f, W2f, flag);
  prep2<<<640, 256, 0, stream>>>(hS, hV, W1b, W1f, Zb, U, (const unsigned*)Ei, flag);
  fusedF<<<256, 256, 0, stream>>>(hE, Ei, mk, hV, W2b, lng, lnb,
                                  W1f, W2f, Zb, U, flag, (float*)d_out);
}

// Round 10
// 94.274 us; speedup vs baseline: 1.1428x; 1.1428x over previous
//
#include <hip/hip_runtime.h>
#include <math.h>

typedef float f32x4 __attribute__((ext_vector_type(4)));
typedef short s16x8 __attribute__((ext_vector_type(8)));
typedef unsigned u32x4 __attribute__((ext_vector_type(4)));

#define N_NODES 2048
#define KEDGE 32
#define HDIM 128
#define SB() __builtin_amdgcn_sched_barrier(0)

__device__ __forceinline__ short f2bf(float f){
  unsigned u = __builtin_bit_cast(unsigned, f);
  u += 0x7fffu + ((u >> 16) & 1u);
  return (short)(u >> 16);
}
__device__ __forceinline__ float bf2f(short s){
  unsigned u = ((unsigned)(unsigned short)s) << 16;
  return __builtin_bit_cast(float, u);
}
__device__ __forceinline__ unsigned cvt_pk_bf16(float a, float b){
  unsigned r;
  asm("v_cvt_pk_bf16_f32 %0, %1, %2" : "=v"(r) : "v"(a), "v"(b));
  return r;
}
// tanh-form GELU via exp2+rcp: max abs error vs exact ~5e-4
__device__ __forceinline__ float fast_gelu(float x){
  float t = x * (-2.3022078f - 0.1029527f * x * x);
  float e = __builtin_amdgcn_exp2f(t);
  return x * __builtin_amdgcn_rcpf(1.0f + e);
}
__device__ __forceinline__ void gld16(const void* g, void* l){
  __builtin_amdgcn_global_load_lds(
      (const __attribute__((address_space(1))) void*)g,
      (__attribute__((address_space(3))) void*)l, 16, 0, 0);
}
__device__ __forceinline__ f32x4 mfma16(s16x8 a, s16x8 b, f32x4 c){
  return __builtin_amdgcn_mfma_f32_16x16x32_bf16(a, b, c, 0, 0, 0);
}

// ---- prep1: pack W1/W2 fp32 -> bf16 MFMA B-frag order; init idx flag ----
// elem((ks,ct,lane,j)) = W[ks*32 + (lane>>4)*8 + j][ct*16 + (lane&15)]
__global__ void prep1(const float* __restrict__ W1, const float* __restrict__ W2,
                      short* __restrict__ W1f, short* __restrict__ W2f,
                      unsigned* __restrict__ flag){
  if (blockIdx.x == 320){
    if (threadIdx.x == 0) *flag = 0u;
    return;
  }
  int t = blockIdx.x * 256 + threadIdx.x;
  if (t < 65536){
    int ks = t >> 12, r = t & 4095;
    int ct = r >> 9;  r &= 511;
    int lane = r >> 3, j = r & 7;
    int k = ks*32 + (lane>>4)*8 + j;
    int n = ct*16 + (lane&15);
    W1f[t] = f2bf(W1[k*128 + n]);
  } else if (t < 81920){
    int t2 = t - 65536;
    int ks = t2 >> 12, r = t2 & 4095;
    int ct = r >> 9;  r &= 511;
    int lane = r >> 3, j = r & 7;
    int k = ks*32 + (lane>>4)*8 + j;
    int n = ct*16 + (lane&15);
    W2f[t2] = f2bf(W2[k*128 + n]);
  }
}

// ---- prep2: Zb (bf16 rows) + UHb (bf16 {U',hV} interleaved, transposed) ----
//   Zb[m][:]              = bf16( hS(m)@W1c + hV(m)@W1d )
//   UHb[m][l15*16+ct*2+0] = bf16( (hV(m)@W1a + b1)[ct*16+l15] )
//   UHb[m][l15*16+ct*2+1] = bf16( hV[m][ct*16+l15] )
// blocks 0..127 compute; 128..639 = E_idx dtype detect.
__global__ __launch_bounds__(256)
void prep2(const float* __restrict__ hS, const float* __restrict__ hV,
           const float* __restrict__ b1, const short* __restrict__ W1f,
           short* __restrict__ Zb, unsigned* __restrict__ UHb,
           const unsigned* __restrict__ Ei_u, unsigned* __restrict__ flag){
  if (blockIdx.x >= 128){
    int t = ((int)blockIdx.x - 128)*256 + threadIdx.x;   // t < 131072
    unsigned v = Ei_u[2*t + 1];
    unsigned long long m = __ballot(v != 0u);
    if ((threadIdx.x & 63) == 0 && m) atomicOr(flag, 1u);
    return;
  }
  const int tid = threadIdx.x;
  const int w = tid >> 6, lane = tid & 63, l15 = lane & 15, lg = lane >> 4;
  const int nb = ((int)blockIdx.x*4 + w)*16;

  f32x4 accz[8], accu[8];
  #pragma unroll
  for (int ct = 0; ct < 8; ++ct){ accz[ct] = (f32x4){0,0,0,0}; accu[ct] = (f32x4){0,0,0,0}; }

  #pragma unroll
  for (int ks = 0; ks < 4; ++ks){
    const float* p = hS + (long)(nb + l15)*128 + ks*32 + lg*8;
    float4 x = *(const float4*)p, y = *(const float4*)(p + 4);
    u32x4 pk;
    pk[0] = cvt_pk_bf16(x.x, x.y); pk[1] = cvt_pk_bf16(x.z, x.w);
    pk[2] = cvt_pk_bf16(y.x, y.y); pk[3] = cvt_pk_bf16(y.z, y.w);
    s16x8 a = __builtin_bit_cast(s16x8, pk);
    #pragma unroll
    for (int ct = 0; ct < 8; ++ct){
      s16x8 bf = *(const s16x8*)(W1f + (8+ks)*4096 + ct*512 + lane*8);
      accz[ct] = mfma16(a, bf, accz[ct]);
    }
  }
  #pragma unroll
  for (int ks = 0; ks < 4; ++ks){
    const float* p = hV + (long)(nb + l15)*128 + ks*32 + lg*8;
    float4 x = *(const float4*)p, y = *(const float4*)(p + 4);
    u32x4 pk;
    pk[0] = cvt_pk_bf16(x.x, x.y); pk[1] = cvt_pk_bf16(x.z, x.w);
    pk[2] = cvt_pk_bf16(y.x, y.y); pk[3] = cvt_pk_bf16(y.z, y.w);
    s16x8 a = __builtin_bit_cast(s16x8, pk);
    #pragma unroll
    for (int ct = 0; ct < 8; ++ct){
      s16x8 bfd = *(const s16x8*)(W1f + (12+ks)*4096 + ct*512 + lane*8);
      accz[ct] = mfma16(a, bfd, accz[ct]);
      s16x8 bfa = *(const s16x8*)(W1f + (0+ks)*4096 + ct*512 + lane*8);
      accu[ct] = mfma16(a, bfa, accu[ct]);
    }
  }

  float b1v[8];
  #pragma unroll
  for (int ct = 0; ct < 8; ++ct) b1v[ct] = b1[ct*16 + l15];

  #pragma unroll
  for (int ct = 0; ct < 8; ++ct)
    #pragma unroll
    for (int i = 0; i < 4; ++i){
      const long row = nb + lg*4 + i;
      Zb[row*128 + ct*16 + l15] = f2bf(accz[ct][i]);
      unsigned u16 = (unsigned)(unsigned short)f2bf(accu[ct][i] + b1v[ct]);
      unsigned h16 = (unsigned)(unsigned short)f2bf(hV[row*128 + ct*16 + l15]);
      UHb[row*128 + l15*8 + ct] = u16 | (h16 << 16);
    }
}

// ---- fused: persistent, barrier-free, 2-deep counted-vmcnt pipeline ----
// grid=256 (1 block/CU), 4 waves, 1 wave/SIMD (512-VGPR budget).
// Wave = half-node per iter, 16 iters (8 nodes). W1 B-frags in REGISTERS.
// Per iter FIFO (sched_barrier-pinned): A(4 loads) | stage(8 gld16) |
// zb(4 loads) | s_waitcnt vmcnt(34) | compute (LDS+regs only).
// stage(t) is issued 2 iters before its wait -> full latency cover.
__global__ __launch_bounds__(256, 1)
void fusedF(const float* __restrict__ hE, const int* __restrict__ Eidx,
            const float* __restrict__ mask,
            const float* __restrict__ W2b, const float* __restrict__ lng,
            const float* __restrict__ lnb, const short* __restrict__ W1f,
            const short* __restrict__ W2f, const short* __restrict__ Zb,
            const unsigned* __restrict__ UHb, const unsigned* __restrict__ idx_flag,
            float* __restrict__ out)
{
  // [0,98304): per-wave hE tri-buffer (3 x 8 KB each wave)
  // [98304,131072): W2 staged; [131072,132096): per-wave v-broadcast
  __shared__ __align__(16) char smem[132096];

  const int tid  = threadIdx.x;
  const int w    = tid >> 6;
  const int lane = tid & 63;
  const int l15  = lane & 15;
  const int lg   = lane >> 4;

  const int n0 = ((int)blockIdx.x * 4 + w) * 8;        // 8 nodes per wave
  const long zrow0 = (long)(n0 >> 11) * N_NODES;       // batch base (r8 lesson)

  char* mybuf = smem + w*24576;
  char* W2L   = smem + 98304;
  short* vl   = (short*)(smem + 131072 + w*256);

  // staging source offsets with XOR-swizzle folded into the per-lane source
  // (m173: gld16 dest is linear; pre-swizzle the source). row = 2q+(lane>>5),
  // LDS[row*512+col] = hErow[col ^ ((row&7)<<4)].
  unsigned pre[8];
  #pragma unroll
  for (int q = 0; q < 8; ++q){
    const int r = 2*q + (lane >> 5);
    pre[q] = (unsigned)(r*512 + (((lane & 31)*16) ^ ((r & 7) << 4)));
  }

  // ---- prologue ----
  // W1 B-frags -> registers (128 VGPR)
  s16x8 wf[4][8];
  #pragma unroll
  for (int ks = 0; ks < 4; ++ks)
    #pragma unroll
    for (int ct = 0; ct < 8; ++ct)
      wf[ks][ct] = *(const s16x8*)(W1f + (4+ks)*4096 + ct*512 + lane*8);

  // W2 -> LDS (cooperative, read every 2nd iter)
  #pragma unroll
  for (int q = 0; q < 8; ++q)
    gld16((const char*)W2f + (w*8+q)*1024 + lane*16, W2L + (w*8+q)*1024);

  // epilogue constants
  float w2b8[8], lngv[2], lnbv[2];
  #pragma unroll
  for (int ct = 0; ct < 8; ++ct) w2b8[ct] = W2b[ct*16 + l15];
  #pragma unroll
  for (int q = 0; q < 2; ++q){
    const int c = (lg*2 + q)*16 + l15;
    lngv[q] = lng[c]; lnbv[q] = lnb[c];
  }

  // identity B-frags for Z injection (exact in bf16)
  s16x8 ifr[2];
  #pragma unroll
  for (int c2 = 0; c2 < 2; ++c2){
    const int active = ((lg >> 1) == c2);
    const int j = l15 - 8*(lg & 1);
    s16x8 f;
    #pragma unroll
    for (int e = 0; e < 8; ++e)
      f[e] = (active && j == e) ? (short)0x3F80 : (short)0;
    ifr[c2] = f;
  }

  const int is64 = (*idx_flag == 0u);

  // stage halves 0,1 into slots 0,1
  #pragma unroll
  for (int hf = 0; hf < 2; ++hf){
    const size_t eb = (size_t)(n0 + (hf>>1))*16384 + (size_t)(hf&1)*8192;
    #pragma unroll
    for (int q = 0; q < 8; ++q)
      gld16((const char*)hE + eb + pre[q], mybuf + hf*8192 + q*1024);
  }

  // pipeline register state: C = it, N1 = it+1, N2 = it+2
  float maskC, maskN1, maskN2;
  s16x8 uhC[2], uhN1[2], uhN2[2];
  s16x8 zbC[4], zbN1[4], zbN2[4];
  int eN2, eN3;
  {
    const int e0i = n0*32 + 0*16 + l15;              // half 0
    const int e1i = n0*32 + 1*16 + l15;              // half 1
    const int e2i = (n0+1)*32 + 0*16 + l15;          // half 2
    const int ea = is64 ? Eidx[2*e0i] : Eidx[e0i];
    const int eb = is64 ? Eidx[2*e1i] : Eidx[e1i];
    eN2 = is64 ? Eidx[2*e2i] : Eidx[e2i];
    maskC  = mask[e0i];
    maskN1 = mask[e1i];
    #pragma unroll
    for (int ks = 0; ks < 4; ++ks){
      zbC[ks]  = *(const s16x8*)(Zb + (zrow0 + ea)*128 + ks*32 + lg*8);
      zbN1[ks] = *(const s16x8*)(Zb + (zrow0 + eb)*128 + ks*32 + lg*8);
    }
    uhC[0]  = *(const s16x8*)((const short*)UHb + (long)n0*256 + l15*16);
    uhC[1]  = *(const s16x8*)((const short*)UHb + (long)n0*256 + l15*16 + 8);
    uhN1[0] = uhC[0]; uhN1[1] = uhC[1];              // same node for half 1
  }

  asm volatile("s_waitcnt vmcnt(0)" ::: "memory");   // cold start drain (once)
  SB();
  __builtin_amdgcn_s_barrier();                      // W2L visible

  float vacc[8];
  #pragma unroll
  for (int ct = 0; ct < 8; ++ct) vacc[ct] = 0.f;

  int cs = 0;                                        // compute slot (it % 3)

  #pragma unroll 2
  for (int it = 0; it < 16; ++it){
    // ---- A-part: 4 loads for it+2 (wrapped tail: distinct addrs, no CSE) ----
    const int hfA = (it + 2) & 15;
    const int hfE = (it + 3) & 15;
    const int nA  = n0 + (hfA >> 1);
    SB();
    maskN2 = mask[nA*32 + (hfA&1)*16 + l15];
    uhN2[0] = *(const s16x8*)((const short*)UHb + (long)nA*256 + l15*16);
    uhN2[1] = *(const s16x8*)((const short*)UHb + (long)nA*256 + l15*16 + 8);
    {
      const int eE = (n0 + (hfE>>1))*32 + (hfE&1)*16 + l15;
      eN3 = is64 ? Eidx[2*eE] : Eidx[eE];
    }
    SB();
    // ---- stage(it+2): exactly 8 gld16 into slot (cs+2)%3 ----
    {
      const int ss = (cs >= 1) ? cs - 1 : 2;         // (cs+2)%3
      char* sbuf = mybuf + ss*8192;
      const size_t eb = (size_t)nA*16384 + (size_t)(hfA&1)*8192;
      #pragma unroll
      for (int q = 0; q < 8; ++q)
        gld16((const char*)hE + eb + pre[q], sbuf + q*1024);
    }
    SB();
    // ---- zb(it+2): 4 gathered b128 from Zb (L2/L3-resident) ----
    #pragma unroll
    for (int ks = 0; ks < 4; ++ks)
      zbN2[ks] = *(const s16x8*)(Zb + (zrow0 + eN2)*128 + ks*32 + lg*8);
    SB();
    // ---- structural wait: stage(it) complete. Exact younger-count = 36
    // (zb(it) 4 + 16 + 16); use 34 for safety margin (stricter = safe). ----
    asm volatile("s_waitcnt vmcnt(34)" ::: "memory");
    SB();

    // ---- compute(it): GEMM1 from LDS slot cs + reg W1 + Z inject ----
    f32x4 acc1[8];
    #pragma unroll
    for (int ct = 0; ct < 8; ++ct) acc1[ct] = (f32x4){0,0,0,0};

    const char* cbuf = mybuf + cs*8192;
    const int sw = (l15 & 7) << 4;
    const int rowb = l15 * 512;
    #pragma unroll
    for (int ks = 0; ks < 4; ++ks){
      const int c0 = ks*128 + lg*32;
      float4 ex = *(const float4*)(cbuf + rowb + (c0 ^ sw));
      float4 ey = *(const float4*)(cbuf + rowb + ((c0 + 16) ^ sw));
      u32x4 pk;
      pk[0] = cvt_pk_bf16(ex.x, ex.y); pk[1] = cvt_pk_bf16(ex.z, ex.w);
      pk[2] = cvt_pk_bf16(ey.x, ey.y); pk[3] = cvt_pk_bf16(ey.z, ey.w);
      s16x8 a = __builtin_bit_cast(s16x8, pk);
      #pragma unroll
      for (int ct = 0; ct < 8; ++ct)
        acc1[ct] = mfma16(a, wf[ks][ct], acc1[ct]);
      #pragma unroll
      for (int c2 = 0; c2 < 2; ++c2)
        acc1[ks*2 + c2] = mfma16(zbC[ks], ifr[c2], acc1[ks*2 + c2]);
    }

    // ---- U' + mask + GELU, accumulate (no reduction yet) ----
    float uv[8];
    #pragma unroll
    for (int ct = 0; ct < 4; ++ct){ uv[ct] = bf2f(uhC[0][2*ct]); uv[4+ct] = bf2f(uhC[1][2*ct]); }
    float mi[4];
    #pragma unroll
    for (int i = 0; i < 4; ++i) mi[i] = __shfl(maskC, lg*4 + i, 64);
    #pragma unroll
    for (int ct = 0; ct < 8; ++ct)
      #pragma unroll
      for (int i = 0; i < 4; ++i)
        vacc[ct] += fast_gelu(uv[ct] + mi[i]*acc1[ct][i]);

    // ---- odd half: reduce, GEMM2, LayerNorm, store ----
    if (it & 1){
      float v8[8];
      #pragma unroll
      for (int ct = 0; ct < 8; ++ct){
        float s = vacc[ct];
        s += __shfl_xor(s, 16, 64);
        s += __shfl_xor(s, 32, 64);
        v8[ct] = s;
        vacc[ct] = 0.f;
      }
      // wave-private v broadcast (r6-verified same-wave fence pattern)
      #pragma unroll
      for (int q = 0; q < 2; ++q){
        const int ct = lg*2 + q;
        vl[ct*16 + l15] = f2bf(v8[ct]);
      }
      asm volatile("s_waitcnt lgkmcnt(0)" ::: "memory");
      SB();

      f32x4 acc2[8];
      #pragma unroll
      for (int ct = 0; ct < 8; ++ct) acc2[ct] = (f32x4){0,0,0,0};
      #pragma unroll
      for (int ks2 = 0; ks2 < 4; ++ks2){
        s16x8 av = *(const s16x8*)((const short*)vl + ks2*32 + lg*8);
        const char* wb2 = W2L + ks2*8192 + lane*16;
        #pragma unroll
        for (int ct = 0; ct < 8; ++ct){
          s16x8 bf = *(const s16x8*)(wb2 + ct*1024);
          acc2[ct] = mfma16(av, bf, acc2[ct]);
        }
      }

      float hv[8];
      #pragma unroll
      for (int ct = 0; ct < 4; ++ct){ hv[ct] = bf2f(uhC[0][2*ct+1]); hv[4+ct] = bf2f(uhC[1][2*ct+1]); }
      float res[8], vs = 0.f, vq = 0.f;
      #pragma unroll
      for (int ct = 0; ct < 8; ++ct){
        float dh  = (acc2[ct][0] + 32.0f * w2b8[ct]) * (1.0f/30.0f);
        float val = hv[ct] + dh;
        res[ct] = val;
        vs += val; vq += val*val;
      }
      vs += __shfl_xor(vs, 1, 64);  vs += __shfl_xor(vs, 2, 64);
      vs += __shfl_xor(vs, 4, 64);  vs += __shfl_xor(vs, 8, 64);
      vq += __shfl_xor(vq, 1, 64);  vq += __shfl_xor(vq, 2, 64);
      vq += __shfl_xor(vq, 4, 64);  vq += __shfl_xor(vq, 8, 64);
      const float mu  = vs * (1.0f/128.0f);
      const float var = vq * (1.0f/128.0f) - mu*mu;
      const float rs  = rsqrtf(var + 1e-5f);

      const long nodeoff = (long)(n0 + (it >> 1)) * HDIM;
      #pragma unroll
      for (int q = 0; q < 2; ++q){
        const int ct = lg*2 + q;
        out[nodeoff + ct*16 + l15] = (res[ct] - mu) * rs * lngv[q] + lnbv[q];
      }
    }

    // ---- rotate pipeline state ----
    maskC = maskN1; maskN1 = maskN2;
    uhC[0] = uhN1[0]; uhC[1] = uhN1[1];
    uhN1[0] = uhN2[0]; uhN1[1] = uhN2[1];
    #pragma unroll
    for (int ks = 0; ks < 4; ++ks){ zbC[ks] = zbN1[ks]; zbN1[ks] = zbN2[ks]; }
    eN2 = eN3;
    cs = (cs == 2) ? 0 : cs + 1;
    SB();
  }
}

extern "C" void kernel_launch(void* const* d_in, const int* in_sizes, int n_in,
                              void* d_out, int out_size, void* d_ws, size_t ws_size,
                              hipStream_t stream) {
  const float* hS  = (const float*)d_in[0];
  const float* hV  = (const float*)d_in[1];
  const float* hE  = (const float*)d_in[2];
  const int*   Ei  = (const int*)d_in[3];
  const float* mk  = (const float*)d_in[4];
  const float* W1w = (const float*)d_in[5];
  const float* W1b = (const float*)d_in[6];
  const float* W2w = (const float*)d_in[7];
  const float* W2b = (const float*)d_in[8];
  const float* lng = (const float*)d_in[9];
  const float* lnb = (const float*)d_in[10];

  short* W1f = (short*)d_ws;                           // 131072 B
  short* W2f = W1f + 65536;                            // 32768 B @131072
  unsigned* flag = (unsigned*)((char*)d_ws + 163840);
  short* Zb = (short*)((char*)d_ws + 164096);          // 2 MB (bf16)
  unsigned* UHb = (unsigned*)((char*)d_ws + 2261248);  // 4 MB (bf16 pairs)
  // total 6.46 MB — under the >=8.6 MB ws confirmed in round 5

  prep1<<<321, 256, 0, stream>>>(W1w, W2w, W1f, W2f, flag);
  prep2<<<640, 256, 0, stream>>>(hS, hV, W1b, W1f, Zb, UHb, (const unsigned*)Ei, flag);
  fusedF<<<256, 256, 0, stream>>>(hE, Ei, mk, W2b, lng, lnb,
                                  W1f, W2f, Zb, UHb, flag, (float*)d_out);
}